// Round 1
// baseline (1437.115 us; speedup 1.0000x reference)
//
#include <hip/hip_runtime.h>
#include <hip/hip_bf16.h>
#include <math.h>

#define B_   2
#define N_   6
#define CC   256
#define OCH  64
#define DBN  59
#define FH_  16
#define FW_  44
#define NPIX (B_*N_*FH_*FW_)       // 8448
#define NPTS (B_*N_*DBN*FH_*FW_)   // 498432
#define NX_  128
#define NY_  128

// linspace steps (compile-time f32, correctly rounded — matches jnp.linspace step)
#define XSTEP (703.0f/43.0f)
#define YSTEP (255.0f/15.0f)

// ---------------------------------------------------------------------------
// Kernel 0: comb[b][n] = rots @ inv(intrins), f32, non-contracted ordering
// ---------------------------------------------------------------------------
__global__ void k_setup_comb(const float* __restrict__ rots,
                             const float* __restrict__ intrins,
                             float* __restrict__ comb) {
    int i = threadIdx.x;
    if (i >= B_ * N_) return;
    const float* K = intrins + i * 9;
    const float* R = rots + i * 9;
    float a = K[0], b = K[1], c = K[2];
    float d = K[3], e = K[4], f = K[5];
    float g = K[6], h = K[7], k = K[8];
    // adjugate / det, all f32 round-to-nearest, no contraction
    float A  =  __fsub_rn(__fmul_rn(e, k), __fmul_rn(f, h));
    float Bc = -__fsub_rn(__fmul_rn(d, k), __fmul_rn(f, g));
    float Cc =  __fsub_rn(__fmul_rn(d, h), __fmul_rn(e, g));
    float det = __fadd_rn(__fadd_rn(__fmul_rn(a, A), __fmul_rn(b, Bc)),
                          __fmul_rn(c, Cc));
    float inv[9];
    inv[0] = __fdiv_rn(A, det);
    inv[1] = __fdiv_rn(-__fsub_rn(__fmul_rn(b, k), __fmul_rn(c, h)), det);
    inv[2] = __fdiv_rn( __fsub_rn(__fmul_rn(b, f), __fmul_rn(c, e)), det);
    inv[3] = __fdiv_rn(Bc, det);
    inv[4] = __fdiv_rn( __fsub_rn(__fmul_rn(a, k), __fmul_rn(c, g)), det);
    inv[5] = __fdiv_rn(-__fsub_rn(__fmul_rn(a, f), __fmul_rn(c, d)), det);
    inv[6] = __fdiv_rn(Cc, det);
    inv[7] = __fdiv_rn(-__fsub_rn(__fmul_rn(a, h), __fmul_rn(b, g)), det);
    inv[8] = __fdiv_rn( __fsub_rn(__fmul_rn(a, e), __fmul_rn(b, d)), det);
    for (int r = 0; r < 3; ++r)
        for (int cc = 0; cc < 3; ++cc) {
            float s =            __fmul_rn(R[r*3+0], inv[0*3+cc]);
            s = __fadd_rn(s,     __fmul_rn(R[r*3+1], inv[1*3+cc]));
            s = __fadd_rn(s,     __fmul_rn(R[r*3+2], inv[2*3+cc]));
            comb[i*9 + r*3 + cc] = s;
        }
}

// ---------------------------------------------------------------------------
// Kernel 1: per-pixel 1x1 conv (256 -> 123) + softmax over first 59 channels.
// One block (128 thr) per pixel. Writes depth_ws[pix][59], ctx_ws[pix][64].
// ---------------------------------------------------------------------------
__global__ __launch_bounds__(128) void k_conv_softmax(
        const float* __restrict__ x, const float* __restrict__ wgt,
        const float* __restrict__ bias,
        float* __restrict__ depth_ws, float* __restrict__ ctx_ws) {
    __shared__ float xs[CC];
    __shared__ float feat[DBN + OCH];
    const int pix = blockIdx.x;            // ((b*N+n)*FH+h)*FW+w
    const int t = threadIdx.x;
    const int wq = pix % FW_;
    const int tmp = pix / FW_;
    const int hq = tmp % FH_;
    const int bn = tmp / FH_;

    const float* xp = x + (size_t)bn * CC * (FH_ * FW_) + hq * FW_ + wq;
    xs[t]        = xp[(size_t)t * (FH_ * FW_)];
    xs[t + 128]  = xp[(size_t)(t + 128) * (FH_ * FW_)];
    __syncthreads();

    if (t < DBN + OCH) {
        const float* wr = wgt + (size_t)t * CC;
        float acc = 0.f;
        #pragma unroll 8
        for (int c = 0; c < CC; ++c) acc = fmaf(xs[c], wr[c], acc);
        feat[t] = acc + bias[t];
    }
    __syncthreads();

    // softmax over feat[0..58] (redundant per-thread; cheap)
    float m = -1e30f;
    for (int d2 = 0; d2 < DBN; ++d2) m = fmaxf(m, feat[d2]);
    float s = 0.f;
    for (int d2 = 0; d2 < DBN; ++d2) s += expf(feat[d2] - m);

    if (t < DBN)
        depth_ws[(size_t)pix * DBN + t] = expf(feat[t] - m) / s;
    if (t >= 64 && t < 64 + OCH)
        ctx_ws[(size_t)pix * OCH + (t - 64)] = feat[DBN + (t - 64)];
}

// ---------------------------------------------------------------------------
// Kernel 2: scatter. One wave per frustum point; lane = output channel.
// ---------------------------------------------------------------------------
__global__ __launch_bounds__(256) void k_scatter(
        const float* __restrict__ depth_ws, const float* __restrict__ ctx_ws,
        const float* __restrict__ comb, const float* __restrict__ trans,
        float* __restrict__ out) {
    const long long tid = (long long)blockIdx.x * 256 + threadIdx.x;
    const int pt = (int)(tid >> 6);
    const int ch = (int)(tid & 63);
    if (pt >= NPTS) return;

    int wq = pt % FW_;  int tmp = pt / FW_;
    int hq = tmp % FH_; tmp /= FH_;
    int dq = tmp % DBN; tmp /= DBN;
    int nq = tmp % N_;  int bq = tmp / N_;
    const int bn = bq * N_ + nq;

    const float* cb = comb + bn * 9;
    const float t0 = trans[bn*3+0], t1 = trans[bn*3+1], t2 = trans[bn*3+2];

    const float dsv = __fadd_rn(1.0f, (float)dq);          // depth value
    const float xsv = __fmul_rn((float)wq, XSTEP);
    const float ysv = __fmul_rn((float)hq, YSTEP);
    const float px = __fmul_rn(xsv, dsv);
    const float py = __fmul_rn(ysv, dsv);
    const float pz = dsv;

    float gx = __fadd_rn(__fadd_rn(__fmul_rn(cb[0], px), __fmul_rn(cb[1], py)),
                         __fmul_rn(cb[2], pz));
    float gy = __fadd_rn(__fadd_rn(__fmul_rn(cb[3], px), __fmul_rn(cb[4], py)),
                         __fmul_rn(cb[5], pz));
    float gz = __fadd_rn(__fadd_rn(__fmul_rn(cb[6], px), __fmul_rn(cb[7], py)),
                         __fmul_rn(cb[8], pz));
    gx = __fadd_rn(gx, t0);
    gy = __fadd_rn(gy, t1);
    gz = __fadd_rn(gz, t2);

    // lb = f32(f32(-50.8) - 0.4) = -51.20000076...  (matches reference folding)
    const float bxv = -50.8f;
    const float lbx = __fsub_rn(bxv, 0.4f);
    const float lby = __fsub_rn(bxv, 0.4f);
    const float lbz = -10.0f;

    const int cx = (int)floorf(__fdiv_rn(__fsub_rn(gx, lbx), 0.8f));
    const int cy = (int)floorf(__fdiv_rn(__fsub_rn(gy, lby), 0.8f));
    const int cz = (int)floorf(__fdiv_rn(__fsub_rn(gz, lbz), 20.0f));

    if (cx >= 0 && cx < NX_ && cy >= 0 && cy < NY_ && cz == 0) {
        const int pix = bn * (FH_ * FW_) + hq * FW_ + wq;
        const float val = __fmul_rn(ctx_ws[(size_t)pix * OCH + ch],
                                    depth_ws[(size_t)pix * DBN + dq]);
        atomicAdd(&out[((size_t)(bq * OCH + ch) * NY_ + cy) * NX_ + cx], val);
    }
}

// ---------------------------------------------------------------------------
extern "C" void kernel_launch(void* const* d_in, const int* in_sizes, int n_in,
                              void* d_out, int out_size, void* d_ws, size_t ws_size,
                              hipStream_t stream) {
    const float* x       = (const float*)d_in[0];
    const float* rots    = (const float*)d_in[1];
    const float* trans   = (const float*)d_in[2];
    const float* intrins = (const float*)d_in[3];
    const float* depth_w = (const float*)d_in[4];
    const float* depth_b = (const float*)d_in[5];
    float* out = (float*)d_out;

    float* ws = (float*)d_ws;
    float* comb     = ws;                       // 108 floats, padded to 128
    float* depth_ws = ws + 128;                 // NPIX*DBN = 498432
    float* ctx_ws   = depth_ws + (size_t)NPIX * DBN;  // NPIX*OCH = 540672

    hipMemsetAsync(d_out, 0, (size_t)out_size * sizeof(float), stream);

    k_setup_comb<<<1, 64, 0, stream>>>(rots, intrins, comb);
    k_conv_softmax<<<NPIX, 128, 0, stream>>>(x, depth_w, depth_b,
                                             depth_ws, ctx_ws);
    const long long total = (long long)NPTS * 64;
    const int blocks = (int)((total + 255) / 256);
    k_scatter<<<blocks, 256, 0, stream>>>(depth_ws, ctx_ws, comb, trans, out);
}

// Round 3
// 365.186 us; speedup vs baseline: 3.9353x; 3.9353x over previous
//
#include <hip/hip_runtime.h>
#include <hip/hip_bf16.h>
#include <math.h>

#define B_   2
#define N_   6
#define CC   256
#define OCH  64
#define DBN  59
#define FH_  16
#define FW_  44
#define PXI  (FH_*FW_)             // 704 pixels per image
#define NPIX (B_*N_*PXI)           // 8448
#define NPTS (B_*N_*DBN*PXI)       // 498432
#define NX_  128
#define NY_  128
#define NCELL (B_*NY_*NX_)         // 32768
#define NOUT 123                   // DBN + OCH

#define XSTEP (703.0f/43.0f)
#define YSTEP (255.0f/15.0f)

// ---------------------------------------------------------------------------
// Kernel 0: comb[b][n] = rots @ inv(intrins), f32, non-contracted ordering
// ---------------------------------------------------------------------------
__global__ void k_setup_comb(const float* __restrict__ rots,
                             const float* __restrict__ intrins,
                             float* __restrict__ comb) {
    int i = threadIdx.x;
    if (i >= B_ * N_) return;
    const float* K = intrins + i * 9;
    const float* R = rots + i * 9;
    float a = K[0], b = K[1], c = K[2];
    float d = K[3], e = K[4], f = K[5];
    float g = K[6], h = K[7], k = K[8];
    float A  =  __fsub_rn(__fmul_rn(e, k), __fmul_rn(f, h));
    float Bc = -__fsub_rn(__fmul_rn(d, k), __fmul_rn(f, g));
    float Cc =  __fsub_rn(__fmul_rn(d, h), __fmul_rn(e, g));
    float det = __fadd_rn(__fadd_rn(__fmul_rn(a, A), __fmul_rn(b, Bc)),
                          __fmul_rn(c, Cc));
    float inv[9];
    inv[0] = __fdiv_rn(A, det);
    inv[1] = __fdiv_rn(-__fsub_rn(__fmul_rn(b, k), __fmul_rn(c, h)), det);
    inv[2] = __fdiv_rn( __fsub_rn(__fmul_rn(b, f), __fmul_rn(c, e)), det);
    inv[3] = __fdiv_rn(Bc, det);
    inv[4] = __fdiv_rn( __fsub_rn(__fmul_rn(a, k), __fmul_rn(c, g)), det);
    inv[5] = __fdiv_rn(-__fsub_rn(__fmul_rn(a, f), __fmul_rn(c, d)), det);
    inv[6] = __fdiv_rn(Cc, det);
    inv[7] = __fdiv_rn(-__fsub_rn(__fmul_rn(a, h), __fmul_rn(b, g)), det);
    inv[8] = __fdiv_rn( __fsub_rn(__fmul_rn(a, e), __fmul_rn(b, d)), det);
    for (int r = 0; r < 3; ++r)
        for (int cc = 0; cc < 3; ++cc) {
            float s =            __fmul_rn(R[r*3+0], inv[0*3+cc]);
            s = __fadd_rn(s,     __fmul_rn(R[r*3+1], inv[1*3+cc]));
            s = __fadd_rn(s,     __fmul_rn(R[r*3+2], inv[2*3+cc]));
            comb[i*9 + r*3 + cc] = s;
        }
}

// ---------------------------------------------------------------------------
// Kernel 1: 1x1 conv as GEMM. wave = (output-group of 4) x (pixel-group of 64).
// 31 o-groups x 132 pixel-groups = 4092 waves = 1023 blocks of 256.
// x reads coalesced (64 consecutive pixels/lane); weights wave-uniform
// (readfirstlane -> s_load). Depth logits -> dlog[d][pix] (coalesced),
// ctx -> ctx_ws[pix][64].
// ---------------------------------------------------------------------------
__global__ __launch_bounds__(256) void k_conv(
        const float* __restrict__ x, const float* __restrict__ wgt,
        const float* __restrict__ bias,
        float* __restrict__ dlog, float* __restrict__ ctx_ws) {
    const int wv = (blockIdx.x * 256 + threadIdx.x) >> 6;
    const int lane = threadIdx.x & 63;
    int og = wv / 132;
    const int pg = wv - og * 132;
    og = __builtin_amdgcn_readfirstlane(og);
    const int o0 = og * 4;
    const int o3 = (o0 + 3 < NOUT) ? (o0 + 3) : (NOUT - 1);
    const int pix = pg * 64 + lane;          // 704 % 64 = 0 -> no bn crossing
    const int bn = pix / PXI;
    const int q  = pix - bn * PXI;
    const float* xp = x + (size_t)bn * CC * PXI + q;
    const float* w0 = wgt + (size_t)o0 * CC;
    const float* w1 = wgt + (size_t)(o0 + 1) * CC;
    const float* w2 = wgt + (size_t)(o0 + 2) * CC;
    const float* w3 = wgt + (size_t)o3 * CC;
    float a0 = 0.f, a1 = 0.f, a2 = 0.f, a3 = 0.f;
    #pragma unroll 8
    for (int c = 0; c < CC; ++c) {
        const float xv = xp[(size_t)c * PXI];
        a0 = fmaf(xv, w0[c], a0);
        a1 = fmaf(xv, w1[c], a1);
        a2 = fmaf(xv, w2[c], a2);
        a3 = fmaf(xv, w3[c], a3);
    }
    a0 += bias[o0]; a1 += bias[o0 + 1]; a2 += bias[o0 + 2]; a3 += bias[o3];
    float av[4] = {a0, a1, a2, a3};
    #pragma unroll
    for (int kk = 0; kk < 4; ++kk) {
        const int o = o0 + kk;
        if (o >= NOUT) break;
        if (o < DBN) dlog[(size_t)o * NPIX + pix] = av[kk];
        else         ctx_ws[(size_t)pix * OCH + (o - DBN)] = av[kk];
    }
}

// ---------------------------------------------------------------------------
// Kernel 2: columnar softmax over the 59 depth logits. Thread = pixel;
// all loads/stores coalesced in [d][pix] layout.
// ---------------------------------------------------------------------------
__global__ __launch_bounds__(256) void k_softmax(
        const float* __restrict__ dlog, float* __restrict__ depth_ws) {
    const int pix = blockIdx.x * 256 + threadIdx.x;
    if (pix >= NPIX) return;
    float v[DBN];
    float m = -1e30f;
    #pragma unroll
    for (int d = 0; d < DBN; ++d) {
        v[d] = dlog[(size_t)d * NPIX + pix];
        m = fmaxf(m, v[d]);
    }
    float s = 0.f;
    #pragma unroll
    for (int d = 0; d < DBN; ++d) { v[d] = expf(v[d] - m); s += v[d]; }
    #pragma unroll
    for (int d = 0; d < DBN; ++d)
        depth_ws[(size_t)d * NPIX + pix] = v[d] / s;
}

// ---------------------------------------------------------------------------
// Shared geometry: point -> cell id (or -1), pix, dq. Bit-identical to the
// validated round-1 FP ordering.
// ---------------------------------------------------------------------------
__device__ __forceinline__ int point_cell(int pt,
                                          const float* __restrict__ comb,
                                          const float* __restrict__ trans,
                                          int* out_pix, int* out_dq) {
    int wq = pt % FW_;  int tmp = pt / FW_;
    int hq = tmp % FH_; tmp /= FH_;
    int dq = tmp % DBN; tmp /= DBN;
    int nq = tmp % N_;  int bq = tmp / N_;
    const int bn = bq * N_ + nq;

    const float* cb = comb + bn * 9;
    const float t0 = trans[bn * 3 + 0], t1 = trans[bn * 3 + 1], t2 = trans[bn * 3 + 2];

    const float dsv = __fadd_rn(1.0f, (float)dq);
    const float xsv = __fmul_rn((float)wq, XSTEP);
    const float ysv = __fmul_rn((float)hq, YSTEP);
    const float px = __fmul_rn(xsv, dsv);
    const float py = __fmul_rn(ysv, dsv);
    const float pz = dsv;

    float gx = __fadd_rn(__fadd_rn(__fmul_rn(cb[0], px), __fmul_rn(cb[1], py)),
                         __fmul_rn(cb[2], pz));
    float gy = __fadd_rn(__fadd_rn(__fmul_rn(cb[3], px), __fmul_rn(cb[4], py)),
                         __fmul_rn(cb[5], pz));
    float gz = __fadd_rn(__fadd_rn(__fmul_rn(cb[6], px), __fmul_rn(cb[7], py)),
                         __fmul_rn(cb[8], pz));
    gx = __fadd_rn(gx, t0);
    gy = __fadd_rn(gy, t1);
    gz = __fadd_rn(gz, t2);

    const float bxv = -50.8f;
    const float lbx = __fsub_rn(bxv, 0.4f);
    const float lbz = -10.0f;

    const int cx = (int)floorf(__fdiv_rn(__fsub_rn(gx, lbx), 0.8f));
    const int cy = (int)floorf(__fdiv_rn(__fsub_rn(gy, lbx), 0.8f));
    const int cz = (int)floorf(__fdiv_rn(__fsub_rn(gz, lbz), 20.0f));

    if (cx >= 0 && cx < NX_ && cy >= 0 && cy < NY_ && cz == 0) {
        *out_pix = bn * PXI + hq * FW_ + wq;
        *out_dq = dq;
        return bq * (NY_ * NX_) + cy * NX_ + cx;
    }
    return -1;
}

// ---------------------------------------------------------------------------
// Kernel 3: histogram of points per cell.
// ---------------------------------------------------------------------------
__global__ __launch_bounds__(256) void k_count(
        const float* __restrict__ comb, const float* __restrict__ trans,
        unsigned* __restrict__ cellofs) {
    const int pt = blockIdx.x * 256 + threadIdx.x;
    if (pt >= NPTS) return;
    int pix, dq;
    const int c = point_cell(pt, comb, trans, &pix, &dq);
    if (c >= 0) atomicAdd(&cellofs[c], 1u);
}

// ---------------------------------------------------------------------------
// Kernel 4: in-place exclusive scan of cellofs[32768]. One block, 1024 thr,
// 32 elems/thread (each thread only rewrites its own 32-elem region).
// ---------------------------------------------------------------------------
__global__ __launch_bounds__(1024) void k_scan(unsigned* __restrict__ cellofs) {
    __shared__ unsigned lds[2][1024];
    const int t = threadIdx.x;
    unsigned v[32];
    unsigned run = 0;
    #pragma unroll
    for (int i = 0; i < 32; ++i) { v[i] = run; run += cellofs[t * 32 + i]; }
    lds[0][t] = run;
    __syncthreads();
    int src = 0;
    for (int off = 1; off < 1024; off <<= 1) {
        unsigned val = lds[src][t];
        if (t >= off) val += lds[src][t - off];
        lds[1 - src][t] = val;
        __syncthreads();
        src = 1 - src;
    }
    const unsigned base = (t == 0) ? 0u : lds[src][t - 1];
    #pragma unroll
    for (int i = 0; i < 32; ++i) cellofs[t * 32 + i] = base + v[i];
}

// ---------------------------------------------------------------------------
// Kernel 5: fill CSR lists. Cursor trick: atomicAdd on cellofs itself; after
// this kernel, cellofs[c] == original exclusive-prefix of c+1 (i.e. end[c]),
// and start[c] == (c ? cellofs[c-1] : 0).
// ---------------------------------------------------------------------------
__global__ __launch_bounds__(256) void k_fill(
        const float* __restrict__ comb, const float* __restrict__ trans,
        const float* __restrict__ depth_ws,
        unsigned* __restrict__ cellofs,
        unsigned* __restrict__ pidx, float* __restrict__ pwgt) {
    const int pt = blockIdx.x * 256 + threadIdx.x;
    if (pt >= NPTS) return;
    int pix, dq;
    const int c = point_cell(pt, comb, trans, &pix, &dq);
    if (c >= 0) {
        const unsigned slot = atomicAdd(&cellofs[c], 1u);
        pidx[slot] = (unsigned)pix;
        pwgt[slot] = depth_ws[(size_t)dq * NPIX + pix];
    }
}

// ---------------------------------------------------------------------------
// Kernel 6: gather. Wave = cell, lane = channel. Broadcast pidx/pwgt loads +
// coalesced 256B ctx reads (all L2-resident). One plain store per output
// element -> full output coverage, no memset, no atomics.
// ---------------------------------------------------------------------------
__global__ __launch_bounds__(256) void k_gather(
        const unsigned* __restrict__ cellofs,
        const unsigned* __restrict__ pidx, const float* __restrict__ pwgt,
        const float* __restrict__ ctx_ws, float* __restrict__ out) {
    const int cell = (int)((blockIdx.x * 256 + threadIdx.x) >> 6);
    const int ch = threadIdx.x & 63;
    if (cell >= NCELL) return;
    const unsigned start = (cell == 0) ? 0u : cellofs[cell - 1];
    const unsigned end = cellofs[cell];
    float acc = 0.f;
    for (unsigned i = start; i < end; ++i) {
        const int pix = (int)pidx[i];
        acc = fmaf(pwgt[i], ctx_ws[(size_t)pix * OCH + ch], acc);
    }
    const int b  = cell >> 14;
    const int cy = (cell >> 7) & 127;
    const int cx = cell & 127;
    out[(((size_t)(b * OCH + ch)) * NY_ + cy) * NX_ + cx] = acc;
}

// ---------------------------------------------------------------------------
extern "C" void kernel_launch(void* const* d_in, const int* in_sizes, int n_in,
                              void* d_out, int out_size, void* d_ws, size_t ws_size,
                              hipStream_t stream) {
    const float* x       = (const float*)d_in[0];
    const float* rots    = (const float*)d_in[1];
    const float* trans   = (const float*)d_in[2];
    const float* intrins = (const float*)d_in[3];
    const float* depth_w = (const float*)d_in[4];
    const float* depth_b = (const float*)d_in[5];
    float* out = (float*)d_out;

    float* ws = (float*)d_ws;
    size_t off = 0;
    float* comb     = ws + off; off += 128;
    float* dlog     = ws + off; off += (size_t)DBN * NPIX;   // 498432
    float* depth_ws = ws + off; off += (size_t)DBN * NPIX;   // 498432
    float* ctx_ws   = ws + off; off += (size_t)NPIX * OCH;   // 540672
    unsigned* cellofs = (unsigned*)(ws + off); off += NCELL; // 32768
    unsigned* pidx  = (unsigned*)(ws + off); off += NPTS;    // 498432
    float* pwgt     = ws + off; off += NPTS;                 // 498432
    // total ~10.3 MB of d_ws

    hipMemsetAsync(cellofs, 0, (size_t)NCELL * sizeof(unsigned), stream);

    k_setup_comb<<<1, 64, 0, stream>>>(rots, intrins, comb);
    k_conv<<<1023, 256, 0, stream>>>(x, depth_w, depth_b, dlog, ctx_ws);
    k_softmax<<<(NPIX + 255) / 256, 256, 0, stream>>>(dlog, depth_ws);
    k_count<<<NPTS / 256, 256, 0, stream>>>(comb, trans, cellofs);
    k_scan<<<1, 1024, 0, stream>>>(cellofs);
    k_fill<<<NPTS / 256, 256, 0, stream>>>(comb, trans, depth_ws, cellofs,
                                           pidx, pwgt);
    k_gather<<<NCELL * 64 / 256, 256, 0, stream>>>(cellofs, pidx, pwgt,
                                                   ctx_ws, out);
}

// Round 4
// 238.463 us; speedup vs baseline: 6.0266x; 1.5314x over previous
//
#include <hip/hip_runtime.h>
#include <hip/hip_bf16.h>
#include <math.h>

#define B_   2
#define N_   6
#define CC   256
#define OCH  64
#define DBN  59
#define FH_  16
#define FW_  44
#define PXI  (FH_*FW_)             // 704
#define NPIX (B_*N_*PXI)           // 8448
#define NPTS (B_*N_*DBN*PXI)       // 498432
#define NX_  128
#define NY_  128
#define NCELL (B_*NY_*NX_)         // 32768
#define NOUT 123
#define OUTSZ (B_*OCH*NY_*NX_)     // 2097152
#define TCH  128                   // gather chunk (slots per wave)

#define XSTEP (703.0f/43.0f)
#define YSTEP (255.0f/15.0f)

// ---------------------------------------------------------------------------
// comb = rots @ inv(intrins): f32, non-contracted, bit-identical to the
// validated round-1/3 ordering.
// ---------------------------------------------------------------------------
__device__ __forceinline__ void comb_cam(const float* __restrict__ R,
                                         const float* __restrict__ K,
                                         float* __restrict__ out9) {
    float a = K[0], b = K[1], c = K[2];
    float d = K[3], e = K[4], f = K[5];
    float g = K[6], h = K[7], k = K[8];
    float A  =  __fsub_rn(__fmul_rn(e, k), __fmul_rn(f, h));
    float Bc = -__fsub_rn(__fmul_rn(d, k), __fmul_rn(f, g));
    float Cc =  __fsub_rn(__fmul_rn(d, h), __fmul_rn(e, g));
    float det = __fadd_rn(__fadd_rn(__fmul_rn(a, A), __fmul_rn(b, Bc)),
                          __fmul_rn(c, Cc));
    float inv[9];
    inv[0] = __fdiv_rn(A, det);
    inv[1] = __fdiv_rn(-__fsub_rn(__fmul_rn(b, k), __fmul_rn(c, h)), det);
    inv[2] = __fdiv_rn( __fsub_rn(__fmul_rn(b, f), __fmul_rn(c, e)), det);
    inv[3] = __fdiv_rn(Bc, det);
    inv[4] = __fdiv_rn( __fsub_rn(__fmul_rn(a, k), __fmul_rn(c, g)), det);
    inv[5] = __fdiv_rn(-__fsub_rn(__fmul_rn(a, f), __fmul_rn(c, d)), det);
    inv[6] = __fdiv_rn(Cc, det);
    inv[7] = __fdiv_rn(-__fsub_rn(__fmul_rn(a, h), __fmul_rn(b, g)), det);
    inv[8] = __fdiv_rn( __fsub_rn(__fmul_rn(a, e), __fmul_rn(b, d)), det);
    for (int r = 0; r < 3; ++r)
        for (int cc = 0; cc < 3; ++cc) {
            float s =        __fmul_rn(R[r*3+0], inv[0*3+cc]);
            s = __fadd_rn(s, __fmul_rn(R[r*3+1], inv[1*3+cc]));
            s = __fadd_rn(s, __fmul_rn(R[r*3+2], inv[2*3+cc]));
            out9[r*3 + cc] = s;
        }
}

// ---------------------------------------------------------------------------
// Kernel 1: 1x1 conv (256 -> 123) + zero-fill of out and cellofs.
// ---------------------------------------------------------------------------
__global__ __launch_bounds__(256) void k_conv(
        const float* __restrict__ x, const float* __restrict__ wgt,
        const float* __restrict__ bias,
        float* __restrict__ dlog, float* __restrict__ ctx_ws,
        float* __restrict__ out, unsigned* __restrict__ cellofs) {
    const int gid = blockIdx.x * 256 + threadIdx.x;
    const int stride = 1023 * 256;
    float4* o4 = (float4*)out;
    for (int i = gid; i < OUTSZ / 4; i += stride)
        o4[i] = make_float4(0.f, 0.f, 0.f, 0.f);
    for (int i = gid; i < NCELL; i += stride) cellofs[i] = 0u;

    const int wv = gid >> 6;
    const int lane = threadIdx.x & 63;
    int og = wv / 132;
    const int pg = wv - og * 132;
    og = __builtin_amdgcn_readfirstlane(og);
    const int o0 = og * 4;
    const int o3 = (o0 + 3 < NOUT) ? (o0 + 3) : (NOUT - 1);
    const int pix = pg * 64 + lane;
    const int bn = pix / PXI;
    const int q  = pix - bn * PXI;
    const float* xp = x + (size_t)bn * CC * PXI + q;
    const float* w0 = wgt + (size_t)o0 * CC;
    const float* w1 = wgt + (size_t)(o0 + 1) * CC;
    const float* w2 = wgt + (size_t)(o0 + 2) * CC;
    const float* w3 = wgt + (size_t)o3 * CC;
    float a0 = 0.f, a1 = 0.f, a2 = 0.f, a3 = 0.f;
    #pragma unroll 8
    for (int c = 0; c < CC; ++c) {
        const float xv = xp[(size_t)c * PXI];
        a0 = fmaf(xv, w0[c], a0);
        a1 = fmaf(xv, w1[c], a1);
        a2 = fmaf(xv, w2[c], a2);
        a3 = fmaf(xv, w3[c], a3);
    }
    a0 += bias[o0]; a1 += bias[o0 + 1]; a2 += bias[o0 + 2]; a3 += bias[o3];
    float av[4] = {a0, a1, a2, a3};
    #pragma unroll
    for (int kk = 0; kk < 4; ++kk) {
        const int o = o0 + kk;
        if (o >= NOUT) break;
        if (o < DBN) dlog[(size_t)o * NPIX + pix] = av[kk];
        else         ctx_ws[(size_t)pix * OCH + (o - DBN)] = av[kk];
    }
}

// ---------------------------------------------------------------------------
// Kernel 2: per-pixel softmax + geometry + histogram. thread = pixel.
// ---------------------------------------------------------------------------
__global__ __launch_bounds__(256) void k_sm_count(
        const float* __restrict__ dlog,
        const float* __restrict__ rots, const float* __restrict__ intrins,
        const float* __restrict__ trans,
        float* __restrict__ depth_ws, unsigned short* __restrict__ cell16,
        unsigned* __restrict__ cellofs) {
    __shared__ float combs[B_ * N_ * 9];
    __shared__ float trs[B_ * N_ * 3];
    const int t = threadIdx.x;
    if (t < B_ * N_) comb_cam(rots + t * 9, intrins + t * 9, &combs[t * 9]);
    if (t < B_ * N_ * 3) trs[t] = trans[t];
    __syncthreads();

    const int pix = blockIdx.x * 256 + t;          // 33*256 == 8448 exact
    const int bn = pix / PXI;
    const int q  = pix - bn * PXI;
    const int hq = q / FW_;
    const int wq = q - hq * FW_;

    float v[DBN];
    float m = -1e30f;
    #pragma unroll
    for (int d = 0; d < DBN; ++d) {
        v[d] = dlog[(size_t)d * NPIX + pix];
        m = fmaxf(m, v[d]);
    }
    float s = 0.f;
    #pragma unroll
    for (int d = 0; d < DBN; ++d) { v[d] = expf(v[d] - m); s += v[d]; }

    const float* cb = &combs[bn * 9];
    const float t0 = trs[bn * 3 + 0], t1 = trs[bn * 3 + 1], t2 = trs[bn * 3 + 2];
    const float xsv = __fmul_rn((float)wq, XSTEP);
    const float ysv = __fmul_rn((float)hq, YSTEP);
    const float bxv = -50.8f;
    const float lbx = __fsub_rn(bxv, 0.4f);
    const float lbz = -10.0f;
    const int bq = bn / N_;

    for (int d = 0; d < DBN; ++d) {
        depth_ws[(size_t)d * NPIX + pix] = v[d] / s;

        const float dsv = __fadd_rn(1.0f, (float)d);
        const float px = __fmul_rn(xsv, dsv);
        const float py = __fmul_rn(ysv, dsv);
        const float pz = dsv;
        float gx = __fadd_rn(__fadd_rn(__fmul_rn(cb[0], px), __fmul_rn(cb[1], py)),
                             __fmul_rn(cb[2], pz));
        float gy = __fadd_rn(__fadd_rn(__fmul_rn(cb[3], px), __fmul_rn(cb[4], py)),
                             __fmul_rn(cb[5], pz));
        float gz = __fadd_rn(__fadd_rn(__fmul_rn(cb[6], px), __fmul_rn(cb[7], py)),
                             __fmul_rn(cb[8], pz));
        gx = __fadd_rn(gx, t0);
        gy = __fadd_rn(gy, t1);
        gz = __fadd_rn(gz, t2);

        const int cx = (int)floorf(__fdiv_rn(__fsub_rn(gx, lbx), 0.8f));
        const int cy = (int)floorf(__fdiv_rn(__fsub_rn(gy, lbx), 0.8f));
        const int cz = (int)floorf(__fdiv_rn(__fsub_rn(gz, lbz), 20.0f));

        unsigned short cc = 0xFFFFu;
        if (cx >= 0 && cx < NX_ && cy >= 0 && cy < NY_ && cz == 0) {
            const int c = bq * (NY_ * NX_) + cy * NX_ + cx;
            cc = (unsigned short)c;
            atomicAdd(&cellofs[c], 1u);
        }
        cell16[(size_t)(bn * DBN + d) * PXI + q] = cc;
    }
}

// ---------------------------------------------------------------------------
// Kernel 3: in-place exclusive scan of cellofs[32768]. One block, 1024 thr.
// ---------------------------------------------------------------------------
__global__ __launch_bounds__(1024) void k_scan(unsigned* __restrict__ cellofs) {
    __shared__ unsigned lds[2][1024];
    const int t = threadIdx.x;
    uint4 u[8];
    const uint4* src4 = (const uint4*)cellofs + (size_t)t * 8;
    #pragma unroll
    for (int i = 0; i < 8; ++i) u[i] = src4[i];
    unsigned vv[32];
    unsigned run = 0;
    #pragma unroll
    for (int i = 0; i < 8; ++i) {
        vv[i*4+0] = run; run += u[i].x;
        vv[i*4+1] = run; run += u[i].y;
        vv[i*4+2] = run; run += u[i].z;
        vv[i*4+3] = run; run += u[i].w;
    }
    lds[0][t] = run;
    __syncthreads();
    int src = 0;
    for (int off = 1; off < 1024; off <<= 1) {
        unsigned val = lds[src][t];
        if (t >= off) val += lds[src][t - off];
        lds[1 - src][t] = val;
        __syncthreads();
        src = 1 - src;
    }
    const unsigned base = (t == 0) ? 0u : lds[src][t - 1];
    uint4* dst4 = (uint4*)cellofs + (size_t)t * 8;
    #pragma unroll
    for (int i = 0; i < 8; ++i) {
        uint4 w;
        w.x = base + vv[i*4+0];
        w.y = base + vv[i*4+1];
        w.z = base + vv[i*4+2];
        w.w = base + vv[i*4+3];
        dst4[i] = w;
    }
}

// ---------------------------------------------------------------------------
// Kernel 4: fill CSR slots from cell16.
// ---------------------------------------------------------------------------
__global__ __launch_bounds__(256) void k_fill(
        const unsigned short* __restrict__ cell16,
        const float* __restrict__ depth_ws,
        unsigned* __restrict__ cellofs,
        unsigned* __restrict__ rec, float* __restrict__ pwgt) {
    const int pt = blockIdx.x * 256 + threadIdx.x;   // 1947*256 == NPTS exact
    const unsigned cc = cell16[pt];
    if (cc == 0xFFFFu) return;
    const int q  = pt % PXI;
    const int r  = pt / PXI;
    const int dq = r % DBN;
    const int bn = r / DBN;
    const int pix = bn * PXI + q;
    const unsigned slot = atomicAdd(&cellofs[cc], 1u);
    rec[slot]  = (cc << 14) | (unsigned)pix;
    pwgt[slot] = depth_ws[(size_t)dq * NPIX + pix];
}

// ---------------------------------------------------------------------------
// Kernel 5: load-balanced chunked gather. wave = 128-slot chunk, lane = ch.
// ---------------------------------------------------------------------------
__device__ __forceinline__ void flush_cell(float* __restrict__ out, int cell,
                                           int ch, float acc, bool use_atomic) {
    const int b  = cell >> 14;
    const int cy = (cell >> 7) & 127;
    const int cx = cell & 127;
    float* dst = &out[(((size_t)(b * OCH + ch)) * NY_ + cy) * NX_ + cx];
    if (use_atomic) atomicAdd(dst, acc);
    else            *dst = acc;
}

__global__ __launch_bounds__(256) void k_gather(
        const unsigned* __restrict__ cellofs,
        const unsigned* __restrict__ rec, const float* __restrict__ pwgt,
        const float* __restrict__ ctx_ws, float* __restrict__ out) {
    const int wid = __builtin_amdgcn_readfirstlane(
                        (blockIdx.x * 256 + threadIdx.x) >> 6);
    const int ch = threadIdx.x & 63;
    const unsigned K = cellofs[NCELL - 1];
    unsigned i = (unsigned)wid * TCH;
    if (i >= K) return;
    const unsigned s1 = (i + TCH < K) ? (i + TCH) : K;

    int cur = (int)(rec[i] >> 14);
    float acc = 0.f;
    bool flushed = false;

    while (i + 8 <= s1) {
        unsigned r8[8]; float w8[8], v8[8];
        #pragma unroll
        for (int j = 0; j < 8; ++j) { r8[j] = rec[i + j]; w8[j] = pwgt[i + j]; }
        #pragma unroll
        for (int j = 0; j < 8; ++j)
            v8[j] = ctx_ws[(size_t)(r8[j] & 0x3FFFu) * OCH + ch];
        #pragma unroll
        for (int j = 0; j < 8; ++j) {
            const int c = (int)(r8[j] >> 14);
            if (c != cur) {
                flush_cell(out, cur, ch, acc, !flushed);
                flushed = true;
                acc = 0.f;
                cur = c;
            }
            acc = fmaf(w8[j], v8[j], acc);
        }
        i += 8;
    }
    while (i < s1) {
        const unsigned rr = rec[i];
        const float ww = pwgt[i];
        const float vv = ctx_ws[(size_t)(rr & 0x3FFFu) * OCH + ch];
        const int c = (int)(rr >> 14);
        if (c != cur) {
            flush_cell(out, cur, ch, acc, !flushed);
            flushed = true;
            acc = 0.f;
            cur = c;
        }
        acc = fmaf(ww, vv, acc);
        ++i;
    }
    flush_cell(out, cur, ch, acc, true);
}

// ---------------------------------------------------------------------------
extern "C" void kernel_launch(void* const* d_in, const int* in_sizes, int n_in,
                              void* d_out, int out_size, void* d_ws, size_t ws_size,
                              hipStream_t stream) {
    const float* x       = (const float*)d_in[0];
    const float* rots    = (const float*)d_in[1];
    const float* trans   = (const float*)d_in[2];
    const float* intrins = (const float*)d_in[3];
    const float* depth_w = (const float*)d_in[4];
    const float* depth_b = (const float*)d_in[5];
    float* out = (float*)d_out;

    float* ws = (float*)d_ws;
    size_t off = 0;
    float* dlog     = ws + off;                       // aliased by rec below
    unsigned* rec   = (unsigned*)(ws + off); off += (size_t)DBN * NPIX;
    float* depth_ws = ws + off; off += (size_t)DBN * NPIX;
    float* ctx_ws   = ws + off; off += (size_t)NPIX * OCH;
    unsigned* cellofs = (unsigned*)(ws + off); off += NCELL;
    float* pwgt     = ws + off; off += (size_t)NPTS;
    unsigned short* cell16 = (unsigned short*)(ws + off);
    // ~9.4 MB of d_ws; rec aliases dlog (dlog dead after k_sm_count).

    k_conv<<<1023, 256, 0, stream>>>(x, depth_w, depth_b, dlog, ctx_ws,
                                     out, cellofs);
    k_sm_count<<<NPIX / 256, 256, 0, stream>>>(dlog, rots, intrins, trans,
                                               depth_ws, cell16, cellofs);
    k_scan<<<1, 1024, 0, stream>>>(cellofs);
    k_fill<<<NPTS / 256, 256, 0, stream>>>(cell16, depth_ws, cellofs,
                                           rec, pwgt);
    const int nchunk = (NPTS + TCH - 1) / TCH;
    k_gather<<<(nchunk + 3) / 4, 256, 0, stream>>>(cellofs, rec, pwgt,
                                                   ctx_ws, out);
}